// Round 1
// 7749.138 us; speedup vs baseline: 2.2219x; 2.2219x over previous
//
#include <hip/hip_runtime.h>
#include <stdint.h>

// LSTMClassifier: 2-layer LSTM (B=128,T=1024,I=256,H=512) + FC(512->1).
// Persistent grid-resident kernel, layers pipelined (layer1 lags 1 step).
// R6: fence-free IF$-coherent exchange. All cross-block data (h values,
// barrier flags) use RELAXED SYSTEM-scope atomics => global_* sc0 sc1
// (bypass L1+L2, served by Infinity Cache). No buffer_wbl2 / buffer_inv
// anywhere in the step loop:
//   release = s_waitcnt vmcnt(0) (sc1 stores never sit dirty in L2) + flag
//   acquire = the sc1 poll load itself (nothing stale can be read since
//             every shared-data access bypasses the non-coherent caches)
// Side effect: x / weights / biases stay L1/L2-resident across steps
// (R5's per-step buffer_inv evicted them every iteration).
//
// ws layout (bytes):
//   Wp0 [2048][768]  bf16 packed rows r=u*4+q  (cols: 0..255=W_ih0, 256..767=W_hh0)
//   Wp1 [2048][1024] bf16 packed                (cols: 0..511=W_ih1, 512..1023=W_hh1)
//   bp0/bp1 [2048] f32 (b_ih+b_hh, packed order)
//   h    ushort[4][128*512]: h0[0],h0[1],h1[0],h1[1] (ping-pong per macro-step)
//   cnt  barrier slots: 8 groups x 64 dwords (one single-writer slot per block)

#define T_STEPS 1024
#define NBLK 512
#define NTHR 256

#define WS_WP0   0u
#define WS_WP1   3145728u
#define WS_BP0   7340032u
#define WS_BP1   7348224u
#define WS_H     7356416u
#define WS_CNT   7880704u
#define CNT_U32  512         // 8 groups x 64 slots

typedef __bf16 bf16x8 __attribute__((ext_vector_type(8)));
typedef float  f32x4  __attribute__((ext_vector_type(4)));
typedef unsigned long long ull;
typedef ull u64x2 __attribute__((ext_vector_type(2)));

__device__ __forceinline__ unsigned short f2bf(float f) {
    union { float f; uint32_t u; } a; a.f = f;
    uint32_t r = a.u + 0x7fffu + ((a.u >> 16) & 1u);
    return (unsigned short)(r >> 16);
}
__device__ __forceinline__ float bf2f(unsigned short u) {
    union { uint32_t u; float f; } a; a.u = ((uint32_t)u) << 16; return a.f;
}
__device__ __forceinline__ float sigm(float x)  { return 1.f / (1.f + __expf(-x)); }
__device__ __forceinline__ float tanh_f(float x){ return 2.f / (1.f + __expf(-2.f * x)) - 1.f; }

// IF$-coherent (L1+L2-bypassing) accessors: relaxed system atomics -> sc0 sc1
__device__ __forceinline__ bf16x8 ld_h16(const unsigned short* p) {
    u64x2 t;
    t.x = __hip_atomic_load((const ull*)p,       __ATOMIC_RELAXED, __HIP_MEMORY_SCOPE_SYSTEM);
    t.y = __hip_atomic_load((const ull*)(p + 4), __ATOMIC_RELAXED, __HIP_MEMORY_SCOPE_SYSTEM);
    return __builtin_bit_cast(bf16x8, t);
}
__device__ __forceinline__ void st_sys_u32(unsigned* p, unsigned v) {
    __hip_atomic_store(p, v, __ATOMIC_RELAXED, __HIP_MEMORY_SCOPE_SYSTEM);
}
__device__ __forceinline__ unsigned ld_sys_u32(const unsigned* p) {
    return __hip_atomic_load(p, __ATOMIC_RELAXED, __HIP_MEMORY_SCOPE_SYSTEM);
}

// ---- pre-pack weights to bf16, gate-interleaved rows r = u*4 + q (q: i,f,g,o) ----
__global__ void k_pack(const float* __restrict__ Wih0, const float* __restrict__ Whh0,
                       const float* __restrict__ Wih1, const float* __restrict__ Whh1,
                       unsigned short* __restrict__ Wp0, unsigned short* __restrict__ Wp1)
{
    int t = blockIdx.x * blockDim.x + threadIdx.x;
    const int N0 = 2048 * 768;
    const int N1 = 2048 * 1024;
    if (t < N0) {
        int r = t / 768, k = t - r * 768;
        int u = r >> 2, q = r & 3, row = q * 512 + u;
        float v = (k < 256) ? Wih0[row * 256 + k] : Whh0[row * 512 + (k - 256)];
        Wp0[t] = f2bf(v);
    } else if (t < N0 + N1) {
        int t2 = t - N0;
        int r = t2 >> 10, k = t2 & 1023;
        int u = r >> 2, q = r & 3, row = q * 512 + u;
        float v = (k < 512) ? Wih1[row * 512 + k] : Whh1[row * 512 + (k - 512)];
        Wp1[t2] = f2bf(v);
    }
}

// ---- biases (packed), zero h ping-pong buffers, zero barrier slots ----
__global__ void k_misc(const float* __restrict__ bih0, const float* __restrict__ bhh0,
                       const float* __restrict__ bih1, const float* __restrict__ bhh1,
                       float* __restrict__ bp0, float* __restrict__ bp1,
                       unsigned short* __restrict__ hbufs, unsigned* __restrict__ cnt)
{
    int t = blockIdx.x * blockDim.x + threadIdx.x;
    if (t < 2048) {
        int u = t >> 2, q = t & 3, row = q * 512 + u;
        bp0[t] = bih0[row] + bhh0[row];
    } else if (t < 4096) {
        int r = t - 2048; int u = r >> 2, q = r & 3, row = q * 512 + u;
        bp1[r] = bih1[row] + bhh1[row];
    } else if (t < 4096 + 262144) {
        hbufs[t - 4096] = 0;
    } else if (t < 4096 + 262144 + CNT_U32) {
        cnt[t - (4096 + 262144)] = 0;
    }
}

// ---- persistent LSTM ----
// NKW: ksteps per wave; KTOT: total K; KS: boundary src0/src1; L0: layer-0 flag
template<int NKW, int KTOT, int KS, bool L0>
__device__ __forceinline__ void run_layer(
    int b0, int ut0, int g0, int w, int col, int quad, int tid,
    const float* __restrict__ x,
    const unsigned short* __restrict__ Wp,
    const float* __restrict__ bp,
    unsigned short* h00, unsigned short* h01,
    unsigned short* h10, unsigned short* h11,
    unsigned* slots, int myslot,
    float (*red)[16][68])
{
    const int bA = b0 + col;  // A-fragment row (batch index)

    // B fragments (weights) -> register-resident for the whole run (pinned).
    uint4 Bf[4][NKW];
    #pragma unroll
    for (int f = 0; f < 4; ++f) {
        const unsigned short* wrow = Wp + (g0 + f * 16 + col) * KTOT + w * (NKW * 32) + quad * 8;
        #pragma unroll
        for (int ks = 0; ks < NKW; ++ks)
            Bf[f][ks] = *(const uint4*)(wrow + ks * 32);
    }
    #pragma unroll
    for (int f = 0; f < 4; ++f) {
        #pragma unroll
        for (int ks = 0; ks < NKW; ++ks) {
            uint32_t c0 = Bf[f][ks].x, c1 = Bf[f][ks].y, c2 = Bf[f][ks].z, c3 = Bf[f][ks].w;
            asm volatile("" : "+v"(c0), "+v"(c1), "+v"(c2), "+v"(c3));
            Bf[f][ks].x = c0; Bf[f][ks].y = c1; Bf[f][ks].z = c2; Bf[f][ks].w = c3;
        }
    }

    const int bl = tid >> 4, ul = tid & 15;      // elementwise domain: 16 batch x 16 units
    const f32x4 bias = *(const f32x4*)(bp + g0 + ul * 4);
    float c = 0.f;                               // cell state, register-resident

    // Per-kstep A source offsets (frag never straddles the KS boundary: 32 | KS)
    int  offA[NKW];
    bool s0[NKW];
    #pragma unroll
    for (int ks = 0; ks < NKW; ++ks) {
        int kg = w * (NKW * 32) + ks * 32 + quad * 8;
        if (kg < KS) { s0[ks] = true;  offA[ks] = L0 ? (bA * (T_STEPS * 256) + kg) : (bA * 512 + kg); }
        else         { s0[ks] = false; offA[ks] = bA * 512 + (kg - KS); }
    }

    unsigned short* h0b[2] = { h00, h01 };
    unsigned short* h1b[2] = { h10, h11 };
    int rp = 0;

    for (int s = 0; s <= T_STEPS; ++s) {
        const bool active = L0 ? (s < T_STEPS) : (s >= 1);
        const unsigned short* h0r = h0b[rp];
        const unsigned short* h1r = h1b[rp];

        if (active) {
            const int t = L0 ? s : (s - 1);
            bf16x8 Af[NKW];
            if (L0) {
                const float* xb = x + t * 256;
                #pragma unroll
                for (int ks = 0; ks < NKW; ++ks) {
                    if (s0[ks]) {   // x source: fp32 -> bf16 on the fly (plain cached loads)
                        const float* p = xb + offA[ks];
                        float4 lo = *(const float4*)p;
                        float4 hi = *(const float4*)(p + 4);
                        bf16x8 v;
                        v[0]=(__bf16)lo.x; v[1]=(__bf16)lo.y; v[2]=(__bf16)lo.z; v[3]=(__bf16)lo.w;
                        v[4]=(__bf16)hi.x; v[5]=(__bf16)hi.y; v[6]=(__bf16)hi.z; v[7]=(__bf16)hi.w;
                        Af[ks] = v;
                    } else {        // h source: IF$-coherent load
                        Af[ks] = ld_h16(h0r + offA[ks]);
                    }
                }
            } else {
                #pragma unroll
                for (int ks = 0; ks < NKW; ++ks)
                    Af[ks] = ld_h16((s0[ks] ? h0r : h1r) + offA[ks]);
            }

            f32x4 acc[4] = { f32x4{0,0,0,0}, f32x4{0,0,0,0}, f32x4{0,0,0,0}, f32x4{0,0,0,0} };
            #pragma unroll
            for (int ks = 0; ks < NKW; ++ks) {
                #pragma unroll
                for (int f = 0; f < 4; ++f)
                    acc[f] = __builtin_amdgcn_mfma_f32_16x16x32_bf16(
                        Af[ks], __builtin_bit_cast(bf16x8, Bf[f][ks]), acc[f], 0, 0, 0);
            }
            // Dump partials: D row=quad*4+r (batch), col=f*16+col (packed gate)
            #pragma unroll
            for (int f = 0; f < 4; ++f) {
                #pragma unroll
                for (int r = 0; r < 4; ++r)
                    red[w][quad * 4 + r][f * 16 + col] = acc[f][r];
            }
        }
        __syncthreads();
        if (active) {
            f32x4 g = bias;
            #pragma unroll
            for (int ww = 0; ww < 4; ++ww)
                g += *(const f32x4*)&red[ww][bl][ul * 4];
            float ig = sigm(g[0]), fg = sigm(g[1]), gc = tanh_f(g[2]), og = sigm(g[3]);
            c = fg * c + ig * gc;
            float h = og * tanh_f(c);
            // pack adjacent ul lanes -> one 4B IF$-coherent store per pair
            unsigned short hv = f2bf(h);
            unsigned short pv = (unsigned short)__shfl_xor((int)hv, 1);
            if (!(ul & 1)) {
                unsigned short* hw = L0 ? h0b[rp ^ 1] : h1b[rp ^ 1];
                unsigned pk = (unsigned)hv | ((unsigned)pv << 16);
                st_sys_u32((unsigned*)(hw + (b0 + bl) * 512 + ut0 + ul), pk);
            }
        }
        // release: drain own vmem (sc1 stores are IF$-visible once acked; nothing
        // is ever dirty in L2, so no buffer_wbl2 needed)
        asm volatile("s_waitcnt vmcnt(0)" ::: "memory");
        __syncthreads();
        // ONE relaxed flag store per block (sc0 sc1 -> IF$)
        if (tid == 0)
            st_sys_u32(slots + myslot, (unsigned)(s + 1));
        // wave0: parallel poll of all 64 group slots (loads bypass stale L2);
        // no acquire fence needed -- all subsequent h loads are sc0 sc1 too.
        if (tid < 64) {
            const unsigned tgt = (unsigned)(s + 1);
            for (;;) {
                unsigned v = ld_sys_u32(slots + tid);
                if (__all((int)(v >= tgt))) break;
                __builtin_amdgcn_s_sleep(1);
            }
        }
        asm volatile("" ::: "memory");
        __syncthreads();
        rp ^= 1;
    }
}

__global__ __launch_bounds__(NTHR, 2) void lstm_persistent(
    const float* __restrict__ x,
    const unsigned short* __restrict__ Wp0, const unsigned short* __restrict__ Wp1,
    const float* __restrict__ bp0, const float* __restrict__ bp1,
    unsigned short* __restrict__ hb, unsigned* __restrict__ cnt)
{
    __shared__ alignas(16) float red[4][16][68];   // 4 K-split waves x [16b][64g(+pad)]
    const int bid   = blockIdx.x;
    const int g     = bid & 7;          // batch-tile group (independent barrier domain)
    const int rest  = bid >> 3;         // 0..63: pid within group
    const int layer = rest & 1;
    const int ut    = rest >> 1;        // 0..31 unit-tile
    const int b0    = g * 16;
    const int ut0   = ut * 16;
    const int g0    = ut * 64;          // packed gate-row base (= ut0*4)
    const int tid   = threadIdx.x;
    const int w = tid >> 6, lane = tid & 63, col = lane & 15, quad = lane >> 4;

    unsigned* slots = cnt + g * 64;
    const int myslot = rest;

    unsigned short* h00 = hb;
    unsigned short* h01 = hb + 65536;
    unsigned short* h10 = hb + 131072;
    unsigned short* h11 = hb + 196608;

    if (layer == 0)
        run_layer<6, 768, 256, true >(b0, ut0, g0, w, col, quad, tid, x, Wp0, bp0, h00, h01, h10, h11, slots, myslot, red);
    else
        run_layer<8, 1024, 512, false>(b0, ut0, g0, w, col, quad, tid, x, Wp1, bp1, h00, h01, h10, h11, slots, myslot, red);
}

// ---- final FC head: logits[b] = h1_T[b,:] . fc_w + fc_b ----
__global__ void k_fc(const unsigned short* __restrict__ h1, const float* __restrict__ fcw,
                     const float* __restrict__ fcb, float* __restrict__ out)
{
    int b = threadIdx.x;
    if (b < 128) {
        const unsigned short* hr = h1 + b * 512;
        float acc = 0.f;
        for (int u = 0; u < 512; ++u) acc += bf2f(hr[u]) * fcw[u];
        out[b] = acc + fcb[0];
    }
}

extern "C" void kernel_launch(void* const* d_in, const int* in_sizes, int n_in,
                              void* d_out, int out_size, void* d_ws, size_t ws_size,
                              hipStream_t stream)
{
    const float* x    = (const float*)d_in[0];
    const float* Wih0 = (const float*)d_in[1];
    const float* Whh0 = (const float*)d_in[2];
    const float* bih0 = (const float*)d_in[3];
    const float* bhh0 = (const float*)d_in[4];
    const float* Wih1 = (const float*)d_in[5];
    const float* Whh1 = (const float*)d_in[6];
    const float* bih1 = (const float*)d_in[7];
    const float* bhh1 = (const float*)d_in[8];
    const float* fcw  = (const float*)d_in[9];
    const float* fcb  = (const float*)d_in[10];

    char* ws = (char*)d_ws;
    unsigned short* Wp0 = (unsigned short*)(ws + WS_WP0);
    unsigned short* Wp1 = (unsigned short*)(ws + WS_WP1);
    float* bp0 = (float*)(ws + WS_BP0);
    float* bp1 = (float*)(ws + WS_BP1);
    unsigned short* hb = (unsigned short*)(ws + WS_H);
    unsigned* cnt = (unsigned*)(ws + WS_CNT);

    const int npack = 2048 * 768 + 2048 * 1024;
    k_pack<<<(npack + 255) / 256, 256, 0, stream>>>(Wih0, Whh0, Wih1, Whh1, Wp0, Wp1);
    const int nmisc = 4096 + 262144 + CNT_U32;
    k_misc<<<(nmisc + 255) / 256, 256, 0, stream>>>(bih0, bhh0, bih1, bhh1, bp0, bp1, hb, cnt);

    lstm_persistent<<<NBLK, NTHR, 0, stream>>>(x, Wp0, Wp1, bp0, bp1, hb, cnt);

    // final h1 lands in ping-pong buffer index 1 (written at macro-step s=1024)
    k_fc<<<1, 128, 0, stream>>>(hb + 196608, fcw, fcb, (float*)d_out);
}